// Round 13
// baseline (761.585 us; speedup 1.0000x reference)
//
#include <hip/hip_runtime.h>
#include <hip/hip_bf16.h>

#define B 64
#define N 1024
#define E 8192
#define EP (E + N)      // 9216 edges incl self-loops
#define C 3
#define H 152
#define NC 10
#define FC_IN 611       // C + 4*H
#define KP 160          // padded H (5 * 32)
#define NT 10           // n-tiles of 16
#define KS 5            // k-steps of 32
#define NFRAG (NT * KS * 64)   // 3200 fragments of 8 bf16
#define TSTRIDE (KS * 64 * 8)  // 2560 elements per 16-row A-tile

typedef __attribute__((ext_vector_type(8))) short bf16x8;
typedef __attribute__((ext_vector_type(4))) float f32x4;

// ---------------- static scratch ----------------
// A operand (layer outputs) in MFMA-fragment-packed order:
// [tile][ks][lane][j]: lane l holds row (l&15), k = ks*32 + (l>>4)*8 + j
__device__ __hip_bfloat16 g_hAfhi[(B * N / 16) * TSTRIDE];
__device__ __hip_bfloat16 g_hAflo[(B * N / 16) * TSTRIDE];
__device__ __hip_bfloat16 g_hBb[B * N][H];         // transformed features (bf16)
__device__ float g_hs[B * N];
__device__ float g_hd[B * N];
__device__ float g_pooled[B * FC_IN];
__device__ __hip_bfloat16 g_Wfhi[3][NFRAG * 8];    // W^T hi, fragment-ordered
__device__ __hip_bfloat16 g_Wflo[3][NFRAG * 8];    // W^T lo, fragment-ordered
__device__ int   g_cnt[B * N];
__device__ int   g_woff[B * N];
__device__ int   g_offs[B * (N + 1)];
__device__ int   g_ssrc[B * EP];

// ---------------- init: zero counters + pack W (merged) ----------------
__global__ void k_init(const float* __restrict__ W234) {
    int gid = blockIdx.x * 256 + threadIdx.x;
    if (gid < B * N) g_cnt[gid] = 0;
    if (gid < B * FC_IN) g_pooled[gid] = 0.f;
    if (gid < 3 * NFRAG * 8) {
        int l = gid / (NFRAG * 8);
        int rem = gid - l * (NFRAG * 8);
        int i = rem >> 3, j = rem & 7;
        int frag = i >> 6, ln = i & 63;
        int nt = frag / KS, ks = frag - nt * KS;
        int n = nt * 16 + (ln & 15);
        int kk = ks * 32 + (ln >> 4) * 8 + j;
        float v = (n < H && kk < H) ? W234[(l * H + kk) * H + n] : 0.f;
        __hip_bfloat16 hi = __float2bfloat16(v);
        float lo = v - __bfloat162float(hi);
        g_Wfhi[l][rem] = hi;
        g_Wflo[l][rem] = __float2bfloat16(lo);
    }
}

// ---------------- CSR build ----------------
__global__ void k_count(const int* __restrict__ ei) {
    int gid = blockIdx.x * 256 + threadIdx.x;
    if (gid >= B * E) return;
    int b = gid >> 13;
    int e = gid & (E - 1);
    int dst = ei[b * 2 * E + E + e];
    atomicAdd(&g_cnt[b * N + dst], 1);
}

__global__ __launch_bounds__(1024) void k_scan() {
    int b = blockIdx.x, t = threadIdx.x;
    __shared__ int s[N];
    int v = g_cnt[b * N + t] + 1;          // +1 self loop
    s[t] = v;
    __syncthreads();
    for (int d = 1; d < N; d <<= 1) {
        int add = (t >= d) ? s[t - d] : 0;
        __syncthreads();
        s[t] += add;
        __syncthreads();
    }
    int incl = s[t], excl = incl - v;
    g_offs[b * (N + 1) + t + 1] = incl;
    if (t == 0) g_offs[b * (N + 1)] = 0;
    g_ssrc[b * EP + excl] = t;             // self loop first in bucket
    g_woff[b * N + t] = excl + 1;
}

__global__ void k_scatter(const int* __restrict__ ei) {
    int gid = blockIdx.x * 256 + threadIdx.x;
    if (gid >= B * E) return;
    int b = gid >> 13;
    int e = gid & (E - 1);
    int src = ei[b * 2 * E + e];
    int dst = ei[b * 2 * E + E + e];
    int pos = atomicAdd(&g_woff[b * N + dst], 1);
    g_ssrc[b * EP + pos] = src;
}

// ---------------- x pooling ----------------
__global__ void k_pool_x(const float* __restrict__ x) {
    int b = blockIdx.x, t = threadIdx.x;
    float a0 = 0, a1 = 0, a2 = 0;
    for (int n = t; n < N; n += 256) {
        const float* p = x + (b * N + n) * C;
        a0 += p[0]; a1 += p[1]; a2 += p[2];
    }
    __shared__ float s[3][256];
    s[0][t] = a0; s[1][t] = a1; s[2][t] = a2;
    __syncthreads();
    for (int d = 128; d > 0; d >>= 1) {
        if (t < d) {
            s[0][t] += s[0][t + d];
            s[1][t] += s[1][t + d];
            s[2][t] += s[2][t + d];
        }
        __syncthreads();
    }
    if (t < 3) g_pooled[b * FC_IN + t] = s[t][0];
}

// ---------------- fused layer 1: h = x @ W1 (K=3) + hs/hd -------------------
__global__ __launch_bounds__(256) void k_layer1(const float* __restrict__ x,
                                                const float* __restrict__ W1,
                                                const float* __restrict__ as_,
                                                const float* __restrict__ ad_) {
    int lane = threadIdx.x & 63, wave = threadIdx.x >> 6;
    int row = blockIdx.x * 4 + wave;       // < B*N
    const float* xr = x + row * C;
    float x0 = xr[0], x1 = xr[1], x2 = xr[2];   // wave-uniform broadcast loads
    __hip_bfloat16* hr = &g_hBb[row][0];
    float vs = 0.f, vd = 0.f;
#pragma unroll
    for (int seg = 0; seg < 3; seg++) {
        int j = lane + seg * 64;
        if (j < H) {
            float h = x0 * W1[j] + x1 * W1[H + j] + x2 * W1[2 * H + j];
            hr[j] = __float2bfloat16(h);
            vs += h * as_[j];
            vd += h * ad_[j];
        }
    }
#pragma unroll
    for (int d = 32; d > 0; d >>= 1) {
        vs += __shfl_xor(vs, d);
        vd += __shfl_xor(vd, d);
    }
    if (lane == 0) { g_hs[row] = vs; g_hd[row] = vd; }
}

// ---------------- split-precision MFMA GEMM + fused hs/hd -------------------
// C = (Ahi+Alo) @ (Whi+Wlo) ~= Ahi*Whi + Alo*Whi + Ahi*Wlo   (f32 accumulate)
__global__ __launch_bounds__(1024, 1) void k_gemm_mfma(int layer, const float* __restrict__ as_,
                                                       const float* __restrict__ ad_) {
    __shared__ short lWhi[NFRAG * 8];   // 51200 B
    __shared__ short lWlo[NFRAG * 8];   // 51200 B
    int tid = threadIdx.x;
    int lane = tid & 63;

    {   // coalesced staging: 16B per thread per iteration
        const __hip_bfloat16* sh = g_Wfhi[layer];
        const __hip_bfloat16* sl = g_Wflo[layer];
        for (int i = tid; i < NFRAG; i += 1024) {
            *(bf16x8*)&lWhi[i * 8] = *(const bf16x8*)&sh[i * 8];
            *(bf16x8*)&lWlo[i * 8] = *(const bf16x8*)&sl[i * 8];
        }
    }
    __syncthreads();

    int tile = blockIdx.x * 16 + (tid >> 6);         // one 16-row tile per wave
    int row0 = tile * 16;
    const __hip_bfloat16* fh = &g_hAfhi[tile * TSTRIDE];
    const __hip_bfloat16* fl = &g_hAflo[tile * TSTRIDE];
    bf16x8 ahi[KS], alo[KS];
#pragma unroll
    for (int ks = 0; ks < KS; ks++) {
        ahi[ks] = *(const bf16x8*)&fh[ks * 512 + lane * 8];   // coalesced 1KB
        alo[ks] = *(const bf16x8*)&fl[ks * 512 + lane * 8];
    }
    f32x4 acc[NT];
#pragma unroll
    for (int nt = 0; nt < NT; nt++) acc[nt] = (f32x4){0.f, 0.f, 0.f, 0.f};
#pragma unroll
    for (int ks = 0; ks < KS; ks++) {
#pragma unroll
        for (int nt = 0; nt < NT; nt++) {
            bf16x8 bh = *(bf16x8*)&lWhi[((nt * KS + ks) * 64 + lane) * 8];
            bf16x8 bl = *(bf16x8*)&lWlo[((nt * KS + ks) * 64 + lane) * 8];
            acc[nt] = __builtin_amdgcn_mfma_f32_16x16x32_bf16(ahi[ks], bh, acc[nt], 0, 0, 0);
            acc[nt] = __builtin_amdgcn_mfma_f32_16x16x32_bf16(alo[ks], bh, acc[nt], 0, 0, 0);
            acc[nt] = __builtin_amdgcn_mfma_f32_16x16x32_bf16(ahi[ks], bl, acc[nt], 0, 0, 0);
        }
    }

    // epilogue: bf16 D store + fused hs/hd (C/D: col=lane&15, row=(lane>>4)*4+reg)
    int col = lane & 15, rg = lane >> 4;
    float ps[4] = {0, 0, 0, 0}, pd[4] = {0, 0, 0, 0};
#pragma unroll
    for (int nt = 0; nt < NT; nt++) {
        int c = nt * 16 + col;
        bool ok = c < H;
        float asv = ok ? as_[c] : 0.f;
        float adv = ok ? ad_[c] : 0.f;
#pragma unroll
        for (int r = 0; r < 4; r++) {
            float v = acc[nt][r];
            if (ok) g_hBb[row0 + rg * 4 + r][c] = __float2bfloat16(v);
            ps[r] += v * asv;
            pd[r] += v * adv;
        }
    }
#pragma unroll
    for (int m = 1; m < 16; m <<= 1) {
#pragma unroll
        for (int r = 0; r < 4; r++) {
            ps[r] += __shfl_xor(ps[r], m);
            pd[r] += __shfl_xor(pd[r], m);
        }
    }
    if (col == 0) {
#pragma unroll
        for (int r = 0; r < 4; r++) {
            g_hs[row0 + rg * 4 + r] = ps[r];
            g_hd[row0 + rg * 4 + r] = pd[r];
        }
    }
}

// ---------------- edge softmax + aggregation + fused pooling ----------------
// 2 waves per dst node (edge-split): both waves compute the lane-parallel
// softmax; each gathers odd/even edges; partials combined in LDS.
// Block = 4 waves = 2 nodes; XCD-swizzled; fragment-packed bf16 hi/lo output.
__global__ __launch_bounds__(256) void k_aggregate(const float* __restrict__ bias, int pool_off) {
    int lane = threadIdx.x & 63, wave = threadIdx.x >> 6;
    int p = wave >> 1;                     // node pair slot (0..1)
    int sub = wave & 1;                    // edge-split half
    // XCD swizzle: each XCD gets 8 whole graphs, graph-sequential
    int bid = blockIdx.x;
    int xcd = bid & 7, slot = bid >> 3;
    int b = xcd + 8 * (slot >> 9);         // graph
    int d = (slot & 511) * 2 + p;          // node within graph
    int node = (b << 10) + d;

    int beg = g_offs[b * (N + 1) + d], end = g_offs[b * (N + 1) + d + 1];
    int deg = end - beg;
    const int* srcs = g_ssrc + b * EP;
    const float* hsb = g_hs + b * N;
    const __hip_bfloat16* hb = &g_hBb[b * N][0];
    float hdv = g_hd[node];

    float a0 = 0.f, a1 = 0.f, a2 = 0.f;
    float denom = 1.f;

    if (deg <= 64) {
        // ---- lane-parallel softmax (both waves, identical result) ----
        int sv = 0;
        float ev = -1e30f;
        if (lane < deg) {
            sv = srcs[beg + lane];
            float e = hsb[sv] + hdv;
            ev = (e > 0.f) ? e : 0.2f * e;
        }
        float m = ev;
#pragma unroll
        for (int s = 32; s > 0; s >>= 1) m = fmaxf(m, __shfl_xor(m, s));
        float wv = (lane < deg) ? __expf(ev - m) : 0.f;
        denom = wv;
#pragma unroll
        for (int s = 32; s > 0; s >>= 1) denom += __shfl_xor(denom, s);

        // ---- this wave gathers edges sub, sub+2, ... (4-way unrolled) ----
        float b0 = 0.f, b1 = 0.f, b2 = 0.f;
        float c0 = 0.f, c1 = 0.f, c2 = 0.f;
        float e0 = 0.f, e1 = 0.f, e2 = 0.f;
        int i = sub;
        for (; i + 6 < deg; i += 8) {
            int s0 = __shfl(sv, i),     s1 = __shfl(sv, i + 2);
            int s2 = __shfl(sv, i + 4), s3 = __shfl(sv, i + 6);
            float w0 = __shfl(wv, i),     w1 = __shfl(wv, i + 2);
            float w2 = __shfl(wv, i + 4), w3 = __shfl(wv, i + 6);
            const __hip_bfloat16* r0 = hb + s0 * H;
            const __hip_bfloat16* r1 = hb + s1 * H;
            const __hip_bfloat16* r2 = hb + s2 * H;
            const __hip_bfloat16* r3 = hb + s3 * H;
            float x00 = __bfloat162float(r0[lane]);
            float x01 = __bfloat162float(r0[lane + 64]);
            float x10 = __bfloat162float(r1[lane]);
            float x11 = __bfloat162float(r1[lane + 64]);
            float x20 = __bfloat162float(r2[lane]);
            float x21 = __bfloat162float(r2[lane + 64]);
            float x30 = __bfloat162float(r3[lane]);
            float x31 = __bfloat162float(r3[lane + 64]);
            float x02 = 0.f, x12 = 0.f, x22 = 0.f, x32 = 0.f;
            if (lane < H - 128) {
                x02 = __bfloat162float(r0[lane + 128]);
                x12 = __bfloat162float(r1[lane + 128]);
                x22 = __bfloat162float(r2[lane + 128]);
                x32 = __bfloat162float(r3[lane + 128]);
            }
            a0 += w0 * x00; a1 += w0 * x01; a2 += w0 * x02;
            b0 += w1 * x10; b1 += w1 * x11; b2 += w1 * x12;
            c0 += w2 * x20; c1 += w2 * x21; c2 += w2 * x22;
            e0 += w3 * x30; e1 += w3 * x31; e2 += w3 * x32;
        }
        for (; i < deg; i += 2) {
            int s0 = __shfl(sv, i);
            float w0 = __shfl(wv, i);
            const __hip_bfloat16* r0 = hb + s0 * H;
            a0 += w0 * __bfloat162float(r0[lane]);
            a1 += w0 * __bfloat162float(r0[lane + 64]);
            if (lane < H - 128) a2 += w0 * __bfloat162float(r0[lane + 128]);
        }
        a0 += b0 + c0 + e0; a1 += b1 + c1 + e1; a2 += b2 + c2 + e2;
    } else {
        // ---- fallback: serial two-pass over all edges; gather own half ----
        float m = -1e30f;
        for (int i = beg; i < end; i++) {
            float e = hsb[srcs[i]] + hdv;
            e = (e > 0.f) ? e : 0.2f * e;
            m = fmaxf(m, e);
        }
        denom = 0.f;
        for (int i = beg; i < end; i++) {
            float e = hsb[srcs[i]] + hdv;
            e = (e > 0.f) ? e : 0.2f * e;
            denom += __expf(e - m);
        }
        for (int i = beg + sub; i < end; i += 2) {
            int s = srcs[i];
            float e = hsb[s] + hdv;
            e = (e > 0.f) ? e : 0.2f * e;
            float w = __expf(e - m);
            const __hip_bfloat16* hr = hb + s * H;
            a0 += w * __bfloat162float(hr[lane]);
            a1 += w * __bfloat162float(hr[lane + 64]);
            if (lane < H - 128) a2 += w * __bfloat162float(hr[lane + 128]);
        }
    }

    // ---- combine the two waves' partials ----
    __shared__ float sp[4][3][64];
    sp[wave][0][lane] = a0;
    sp[wave][1][lane] = a1;
    sp[wave][2][lane] = a2;
    __syncthreads();

    float o0 = 0.f, o1 = 0.f, o2 = 0.f;
    if (sub == 0) {
        float inv = 1.0f / denom;
        o0 = (sp[wave][0][lane] + sp[wave + 1][0][lane]) * inv + bias[lane];
        o1 = (sp[wave][1][lane] + sp[wave + 1][1][lane]) * inv + bias[lane + 64];
        if (lane < H - 128)
            o2 = (sp[wave][2][lane] + sp[wave + 1][2][lane]) * inv + bias[lane + 128];

        // ---- store in MFMA-fragment-packed order ----
        int tile = node >> 4, rt = node & 15;
        __hip_bfloat16* fh = &g_hAfhi[tile * TSTRIDE];
        __hip_bfloat16* fl = &g_hAflo[tile * TSTRIDE];
        {
            int f = lane;
            int idx = (f >> 5) * 512 + (rt + ((f >> 3) & 3) * 16) * 8 + (f & 7);
            __hip_bfloat16 hi = __float2bfloat16(o0);
            fh[idx] = hi; fl[idx] = __float2bfloat16(o0 - __bfloat162float(hi));
        }
        {
            int f = lane + 64;
            int idx = (f >> 5) * 512 + (rt + ((f >> 3) & 3) * 16) * 8 + (f & 7);
            __hip_bfloat16 hi = __float2bfloat16(o1);
            fh[idx] = hi; fl[idx] = __float2bfloat16(o1 - __bfloat162float(hi));
        }
        if (lane < H - 128) {
            int f = lane + 128;
            int idx = (f >> 5) * 512 + (rt + ((f >> 3) & 3) * 16) * 8 + (f & 7);
            __hip_bfloat16 hi = __float2bfloat16(o2);
            fh[idx] = hi; fl[idx] = __float2bfloat16(o2 - __bfloat162float(hi));
        }
        if (lane == 0) {       // zero pad k=152..159 for this node's row
            bf16x8 z = (bf16x8){0, 0, 0, 0, 0, 0, 0, 0};
            *(bf16x8*)&fh[4 * 512 + (rt + 48) * 8] = z;
            *(bf16x8*)&fl[4 * 512 + (rt + 48) * 8] = z;
        }
    }
    __syncthreads();
    if (sub == 0) {
        sp[wave][0][lane] = o0;
        sp[wave][1][lane] = o1;
        sp[wave][2][lane] = o2;
    }
    __syncthreads();
    if (wave == 0) {
        float* pb = g_pooled + b * FC_IN + pool_off;
        atomicAdd(&pb[lane], sp[0][0][lane] + sp[2][0][lane]);
        atomicAdd(&pb[lane + 64], sp[0][1][lane] + sp[2][1][lane]);
        if (lane < H - 128)
            atomicAdd(&pb[lane + 128], sp[0][2][lane] + sp[2][2][lane]);
    }
}

// ---------------- MLP head ----------------
__global__ __launch_bounds__(256) void k_mlp(const float* __restrict__ fc1W, const float* __restrict__ fc1b,
                                             const float* __restrict__ fc2W, const float* __restrict__ fc2b,
                                             const float* __restrict__ fc3W, const float* __restrict__ fc3b,
                                             float* __restrict__ out) {
    int b = blockIdx.x, t = threadIdx.x;
    __shared__ float p[FC_IN];
    __shared__ float h1[256];
    __shared__ float h2[128];
    const float invN = 1.0f / N;
    for (int i = t; i < FC_IN; i += 256) p[i] = g_pooled[b * FC_IN + i] * invN;
    __syncthreads();
    float acc = fc1b[t];
    for (int k = 0; k < FC_IN; k++) acc += p[k] * fc1W[k * 256 + t];
    h1[t] = acc;
    __syncthreads();
    if (t < 128) {
        float a = fc2b[t];
        for (int k = 0; k < 256; k++) a += h1[k] * fc2W[k * 128 + t];
        h2[t] = a;
    }
    __syncthreads();
    if (t < NC) {
        float a = fc3b[t];
        for (int k = 0; k < 128; k++) a += h2[k] * fc3W[k * NC + t];
        out[b * NC + t] = a;
    }
}

// ---------------- launch ----------------
extern "C" void kernel_launch(void* const* d_in, const int* in_sizes, int n_in,
                              void* d_out, int out_size, void* d_ws, size_t ws_size,
                              hipStream_t stream) {
    const float* x    = (const float*)d_in[0];
    const int*   ei   = (const int*)d_in[1];
    const float* W1   = (const float*)d_in[2];
    const float* as1  = (const float*)d_in[3];
    const float* ad1  = (const float*)d_in[4];
    const float* b1   = (const float*)d_in[5];
    const float* W234 = (const float*)d_in[6];
    const float* as234= (const float*)d_in[7];
    const float* ad234= (const float*)d_in[8];
    const float* b234 = (const float*)d_in[9];
    const float* fc1W = (const float*)d_in[10];
    const float* fc1b = (const float*)d_in[11];
    const float* fc2W = (const float*)d_in[12];
    const float* fc2b = (const float*)d_in[13];
    const float* fc3W = (const float*)d_in[14];
    const float* fc3b = (const float*)d_in[15];
    float* out = (float*)d_out;

    hipLaunchKernelGGL(k_init, dim3((3 * NFRAG * 8 + 255) / 256), dim3(256), 0, stream, W234);
    hipLaunchKernelGGL(k_count, dim3((B * E + 255) / 256), dim3(256), 0, stream, ei);
    hipLaunchKernelGGL(k_scan, dim3(B), dim3(1024), 0, stream);
    hipLaunchKernelGGL(k_scatter, dim3((B * E + 255) / 256), dim3(256), 0, stream, ei);
    hipLaunchKernelGGL(k_pool_x, dim3(B), dim3(256), 0, stream, x);

    // Layer 1: fused transform + hs/hd, then aggregate(+pool)
    hipLaunchKernelGGL(k_layer1, dim3(B * N / 4), dim3(256), 0, stream, x, W1, as1, ad1);
    hipLaunchKernelGGL(k_aggregate, dim3(B * N / 2), dim3(256), 0, stream, b1, 3);

    // Layers 2-4: split-precision MFMA GEMM (fused hs/hd) + aggregate(+pool)
    for (int l = 0; l < 3; l++) {
        hipLaunchKernelGGL(k_gemm_mfma, dim3(256), dim3(1024), 0, stream,
                           l, as234 + l * H, ad234 + l * H);
        hipLaunchKernelGGL(k_aggregate, dim3(B * N / 2), dim3(256), 0, stream,
                           b234 + l * H, 3 + H + l * H);
    }

    hipLaunchKernelGGL(k_mlp, dim3(B), dim3(256), 0, stream,
                       fc1W, fc1b, fc2W, fc2b, fc3W, fc3b, out);
}

// Round 14
// 573.617 us; speedup vs baseline: 1.3277x; 1.3277x over previous
//
#include <hip/hip_runtime.h>
#include <hip/hip_bf16.h>

#define B 64
#define N 1024
#define E 8192
#define EP (E + N)      // 9216 edges incl self-loops
#define C 3
#define H 152
#define NC 10
#define FC_IN 611       // C + 4*H
#define NT 10           // n-tiles of 16
#define KS 5            // k-steps of 32
#define NFRAG (NT * KS * 64)   // 3200 fragments of 8 bf16
#define AP 168          // padded A-tile row length (elements)

typedef __attribute__((ext_vector_type(8))) short bf16x8;
typedef __attribute__((ext_vector_type(4))) float f32x4;

// ---------------- static scratch ----------------
__device__ __hip_bfloat16 g_hBb[2][B * N][H];      // transformed features (bf16), dbuf
__device__ float g_hs[2][B * N];
__device__ float g_hd[2][B * N];
__device__ float g_pooled[B * FC_IN];
__device__ __hip_bfloat16 g_Wfhi[3][NFRAG * 8];    // W^T hi, fragment-ordered
__device__ __hip_bfloat16 g_Wflo[3][NFRAG * 8];    // W^T lo residual
__device__ int   g_cnt[B * N];
__device__ int   g_woff[B * N];
__device__ int   g_offs[B * (N + 1)];
__device__ int   g_ssrc[B * EP];

// ---------------- init: zero counters + pack W (merged) ----------------
__global__ void k_init(const float* __restrict__ W234) {
    int gid = blockIdx.x * 256 + threadIdx.x;
    if (gid < B * N) g_cnt[gid] = 0;
    if (gid < B * FC_IN) g_pooled[gid] = 0.f;
    if (gid < 3 * NFRAG * 8) {
        int l = gid / (NFRAG * 8);
        int rem = gid - l * (NFRAG * 8);
        int i = rem >> 3, j = rem & 7;
        int frag = i >> 6, ln = i & 63;
        int nt = frag / KS, ks = frag - nt * KS;
        int n = nt * 16 + (ln & 15);
        int kk = ks * 32 + (ln >> 4) * 8 + j;
        float v = (n < H && kk < H) ? W234[(l * H + kk) * H + n] : 0.f;
        __hip_bfloat16 hi = __float2bfloat16(v);
        float lo = v - __bfloat162float(hi);
        g_Wfhi[l][rem] = hi;
        g_Wflo[l][rem] = __float2bfloat16(lo);
    }
}

// ---------------- CSR build ----------------
__global__ void k_count(const int* __restrict__ ei) {
    int gid = blockIdx.x * 256 + threadIdx.x;
    if (gid >= B * E) return;
    int b = gid >> 13;
    int e = gid & (E - 1);
    int dst = ei[b * 2 * E + E + e];
    atomicAdd(&g_cnt[b * N + dst], 1);
}

__global__ __launch_bounds__(1024) void k_scan() {
    int b = blockIdx.x, t = threadIdx.x;
    __shared__ int s[N];
    int v = g_cnt[b * N + t] + 1;          // +1 self loop
    s[t] = v;
    __syncthreads();
    for (int d = 1; d < N; d <<= 1) {
        int add = (t >= d) ? s[t - d] : 0;
        __syncthreads();
        s[t] += add;
        __syncthreads();
    }
    int incl = s[t], excl = incl - v;
    g_offs[b * (N + 1) + t + 1] = incl;
    if (t == 0) g_offs[b * (N + 1)] = 0;
    g_ssrc[b * EP + excl] = t;             // self loop first in bucket
    g_woff[b * N + t] = excl + 1;
}

__global__ void k_scatter(const int* __restrict__ ei) {
    int gid = blockIdx.x * 256 + threadIdx.x;
    if (gid >= B * E) return;
    int b = gid >> 13;
    int e = gid & (E - 1);
    int src = ei[b * 2 * E + e];
    int dst = ei[b * 2 * E + E + e];
    int pos = atomicAdd(&g_woff[b * N + dst], 1);
    g_ssrc[b * EP + pos] = src;
}

// ---------------- x pooling ----------------
__global__ void k_pool_x(const float* __restrict__ x) {
    int b = blockIdx.x, t = threadIdx.x;
    float a0 = 0, a1 = 0, a2 = 0;
    for (int n = t; n < N; n += 256) {
        const float* p = x + (b * N + n) * C;
        a0 += p[0]; a1 += p[1]; a2 += p[2];
    }
    __shared__ float s[3][256];
    s[0][t] = a0; s[1][t] = a1; s[2][t] = a2;
    __syncthreads();
    for (int d = 128; d > 0; d >>= 1) {
        if (t < d) {
            s[0][t] += s[0][t + d];
            s[1][t] += s[1][t + d];
            s[2][t] += s[2][t + d];
        }
        __syncthreads();
    }
    if (t < 3) g_pooled[b * FC_IN + t] = s[t][0];
}

// ---------------- fused layer 1: h = x @ W1 (K=3) + hs/hd → buffers[0] -----
__global__ __launch_bounds__(256) void k_layer1(const float* __restrict__ x,
                                                const float* __restrict__ W1,
                                                const float* __restrict__ as_,
                                                const float* __restrict__ ad_) {
    int lane = threadIdx.x & 63, wave = threadIdx.x >> 6;
    int row = blockIdx.x * 4 + wave;       // < B*N
    const float* xr = x + row * C;
    float x0 = xr[0], x1 = xr[1], x2 = xr[2];
    __hip_bfloat16* hr = &g_hBb[0][row][0];
    float vs = 0.f, vd = 0.f;
#pragma unroll
    for (int seg = 0; seg < 3; seg++) {
        int j = lane + seg * 64;
        if (j < H) {
            float h = x0 * W1[j] + x1 * W1[H + j] + x2 * W1[2 * H + j];
            hr[j] = __float2bfloat16(h);
            vs += h * as_[j];
            vd += h * ad_[j];
        }
    }
#pragma unroll
    for (int d = 32; d > 0; d >>= 1) {
        vs += __shfl_xor(vs, d);
        vd += __shfl_xor(vd, d);
    }
    if (lane == 0) { g_hs[0][row] = vs; g_hd[0][row] = vd; }
}

// ---------------- FUSED: aggregate(layer k) + GEMM(layer k+1) ---------------
// 256 thr = 4 waves; each wave owns one 16-node tile: per node, R12 softmax +
// gather from hBb[inb]; outputs to per-wave LDS A-tile (bf16 hi/lo, padded);
// then split-precision MFMA against W-fragments read from L2; writes
// hBb[inb^1] + hs/hd[inb^1]. Per-wave pooling of aggregate outputs.
__global__ __launch_bounds__(256) void k_fused(int l, const float* __restrict__ bias,
                                               int pool_off, int inb,
                                               const float* __restrict__ as_,
                                               const float* __restrict__ ad_) {
    __shared__ __hip_bfloat16 sAhi[4][16][AP];   // 21504 B
    __shared__ __hip_bfloat16 sAlo[4][16][AP];   // 21504 B
    int lane = threadIdx.x & 63, wave = threadIdx.x >> 6;
    // graph→XCD chunked: graph g served by XCD g/8 (consistent across layers)
    int bid = blockIdx.x;                  // 0..1023
    int xcd = bid & 7, j = bid >> 3;       // j: 0..127
    int b = xcd * 8 + (j & 7);             // graph
    int part = j >> 3;                     // 0..15
    int d0 = (part * 4 + wave) * 16;       // first node of this wave's tile
    int tile = b * 64 + part * 4 + wave;

    const int* offs = g_offs + b * (N + 1);
    int offl = (lane < 17) ? offs[d0 + lane] : 0;   // preloaded tile offsets
    const int* srcs = g_ssrc + b * EP;
    const float* hsb = g_hs[inb] + b * N;
    const float* hdb = g_hd[inb] + b * N;
    const __hip_bfloat16* hb = &g_hBb[inb][b * N][0];
    float pool0 = 0.f, pool1 = 0.f, pool2 = 0.f;

    // ---------- phase 1: 16 node aggregates into LDS A-tile ----------
    for (int nn = 0; nn < 16; nn++) {
        int beg = __shfl(offl, nn);
        int end = __shfl(offl, nn + 1);
        int deg = end - beg;
        float hdv = hdb[d0 + nn];
        float a0 = 0.f, a1 = 0.f, a2 = 0.f;
        float denom = 1.f;

        if (deg <= 64) {
            int sv = 0;
            float ev = -1e30f;
            if (lane < deg) {
                sv = srcs[beg + lane];
                float e = hsb[sv] + hdv;
                ev = (e > 0.f) ? e : 0.2f * e;
            }
            float m = ev;
#pragma unroll
            for (int s = 32; s > 0; s >>= 1) m = fmaxf(m, __shfl_xor(m, s));
            float wv = (lane < deg) ? __expf(ev - m) : 0.f;
            denom = wv;
#pragma unroll
            for (int s = 32; s > 0; s >>= 1) denom += __shfl_xor(denom, s);

            float b0 = 0.f, b1 = 0.f, b2 = 0.f;
            float c0 = 0.f, c1 = 0.f, c2 = 0.f;
            float e0 = 0.f, e1 = 0.f, e2 = 0.f;
            int i = 0;
            for (; i + 4 <= deg; i += 4) {
                int s0 = __shfl(sv, i),     s1 = __shfl(sv, i + 1);
                int s2 = __shfl(sv, i + 2), s3 = __shfl(sv, i + 3);
                float w0 = __shfl(wv, i),     w1 = __shfl(wv, i + 1);
                float w2 = __shfl(wv, i + 2), w3 = __shfl(wv, i + 3);
                const __hip_bfloat16* r0 = hb + s0 * H;
                const __hip_bfloat16* r1 = hb + s1 * H;
                const __hip_bfloat16* r2 = hb + s2 * H;
                const __hip_bfloat16* r3 = hb + s3 * H;
                float x00 = __bfloat162float(r0[lane]);
                float x01 = __bfloat162float(r0[lane + 64]);
                float x10 = __bfloat162float(r1[lane]);
                float x11 = __bfloat162float(r1[lane + 64]);
                float x20 = __bfloat162float(r2[lane]);
                float x21 = __bfloat162float(r2[lane + 64]);
                float x30 = __bfloat162float(r3[lane]);
                float x31 = __bfloat162float(r3[lane + 64]);
                float x02 = 0.f, x12 = 0.f, x22 = 0.f, x32 = 0.f;
                if (lane < H - 128) {
                    x02 = __bfloat162float(r0[lane + 128]);
                    x12 = __bfloat162float(r1[lane + 128]);
                    x22 = __bfloat162float(r2[lane + 128]);
                    x32 = __bfloat162float(r3[lane + 128]);
                }
                a0 += w0 * x00; a1 += w0 * x01; a2 += w0 * x02;
                b0 += w1 * x10; b1 += w1 * x11; b2 += w1 * x12;
                c0 += w2 * x20; c1 += w2 * x21; c2 += w2 * x22;
                e0 += w3 * x30; e1 += w3 * x31; e2 += w3 * x32;
            }
            for (; i + 2 <= deg; i += 2) {
                int s0 = __shfl(sv, i), s1 = __shfl(sv, i + 1);
                float w0 = __shfl(wv, i), w1 = __shfl(wv, i + 1);
                const __hip_bfloat16* r0 = hb + s0 * H;
                const __hip_bfloat16* r1 = hb + s1 * H;
                float x00 = __bfloat162float(r0[lane]);
                float x01 = __bfloat162float(r0[lane + 64]);
                float x10 = __bfloat162float(r1[lane]);
                float x11 = __bfloat162float(r1[lane + 64]);
                float x02 = 0.f, x12 = 0.f;
                if (lane < H - 128) {
                    x02 = __bfloat162float(r0[lane + 128]);
                    x12 = __bfloat162float(r1[lane + 128]);
                }
                a0 += w0 * x00; a1 += w0 * x01; a2 += w0 * x02;
                b0 += w1 * x10; b1 += w1 * x11; b2 += w1 * x12;
            }
            if (i < deg) {
                int s0 = __shfl(sv, i);
                float w0 = __shfl(wv, i);
                const __hip_bfloat16* r0 = hb + s0 * H;
                a0 += w0 * __bfloat162float(r0[lane]);
                a1 += w0 * __bfloat162float(r0[lane + 64]);
                if (lane < H - 128) a2 += w0 * __bfloat162float(r0[lane + 128]);
            }
            a0 += b0 + c0 + e0; a1 += b1 + c1 + e1; a2 += b2 + c2 + e2;
        } else {
            float m = -1e30f;
            for (int i = beg; i < end; i++) {
                float e = hsb[srcs[i]] + hdv;
                e = (e > 0.f) ? e : 0.2f * e;
                m = fmaxf(m, e);
            }
            denom = 0.f;
            for (int i = beg; i < end; i++) {
                int s = srcs[i];
                float e = hsb[s] + hdv;
                e = (e > 0.f) ? e : 0.2f * e;
                float w = __expf(e - m);
                denom += w;
                const __hip_bfloat16* hr = hb + s * H;
                a0 += w * __bfloat162float(hr[lane]);
                a1 += w * __bfloat162float(hr[lane + 64]);
                if (lane < H - 128) a2 += w * __bfloat162float(hr[lane + 128]);
            }
        }

        float inv = 1.0f / denom;
        float o0 = a0 * inv + bias[lane];
        float o1 = a1 * inv + bias[lane + 64];
        float o2 = (lane < H - 128) ? (a2 * inv + bias[lane + 128]) : 0.f;
        pool0 += o0; pool1 += o1; pool2 += o2;

        __hip_bfloat16 h0 = __float2bfloat16(o0);
        __hip_bfloat16 h1 = __float2bfloat16(o1);
        __hip_bfloat16 h2 = __float2bfloat16(o2);      // 0 on pad lanes
        sAhi[wave][nn][lane] = h0;
        sAlo[wave][nn][lane] = __float2bfloat16(o0 - __bfloat162float(h0));
        sAhi[wave][nn][lane + 64] = h1;
        sAlo[wave][nn][lane + 64] = __float2bfloat16(o1 - __bfloat162float(h1));
        if (lane < AP - 128) {   // lanes 0..39 cover f = 128..167 (zero-padded)
            sAhi[wave][nn][lane + 128] = h2;
            sAlo[wave][nn][lane + 128] = __float2bfloat16(o2 - __bfloat162float(h2));
        }
    }

    // per-wave pooled atomics
    {
        float* pb = g_pooled + b * FC_IN + pool_off;
        atomicAdd(&pb[lane], pool0);
        atomicAdd(&pb[lane + 64], pool1);
        if (lane < H - 128) atomicAdd(&pb[lane + 128], pool2);
    }

    // ---------- phase 2: split-precision MFMA GEMM (W from L2) ----------
    int outb = inb ^ 1;
    const __hip_bfloat16* sAh = &sAhi[wave][0][0];
    const __hip_bfloat16* sAl = &sAlo[wave][0][0];
    bf16x8 ahi[KS], alo[KS];
#pragma unroll
    for (int ks = 0; ks < KS; ks++) {
        int off = (lane & 15) * AP + ks * 32 + (lane >> 4) * 8;
        ahi[ks] = *(const bf16x8*)&sAh[off];
        alo[ks] = *(const bf16x8*)&sAl[off];
    }
    const __hip_bfloat16* Wh = g_Wfhi[l];
    const __hip_bfloat16* Wl = g_Wflo[l];
    f32x4 acc[NT];
#pragma unroll
    for (int nt = 0; nt < NT; nt++) acc[nt] = (f32x4){0.f, 0.f, 0.f, 0.f};
#pragma unroll
    for (int ks = 0; ks < KS; ks++) {
#pragma unroll
        for (int nt = 0; nt < NT; nt++) {
            bf16x8 bh = *(const bf16x8*)&Wh[((nt * KS + ks) * 64 + lane) * 8];
            bf16x8 bl = *(const bf16x8*)&Wl[((nt * KS + ks) * 64 + lane) * 8];
            acc[nt] = __builtin_amdgcn_mfma_f32_16x16x32_bf16(ahi[ks], bh, acc[nt], 0, 0, 0);
            acc[nt] = __builtin_amdgcn_mfma_f32_16x16x32_bf16(alo[ks], bh, acc[nt], 0, 0, 0);
            acc[nt] = __builtin_amdgcn_mfma_f32_16x16x32_bf16(ahi[ks], bl, acc[nt], 0, 0, 0);
        }
    }

    // epilogue: bf16 D store + fused hs/hd (C/D: col=lane&15, row=(lane>>4)*4+reg)
    int row0 = tile * 16;
    int col = lane & 15, rg = lane >> 4;
    float ps[4] = {0, 0, 0, 0}, pd[4] = {0, 0, 0, 0};
#pragma unroll
    for (int nt = 0; nt < NT; nt++) {
        int c = nt * 16 + col;
        bool ok = c < H;
        float asv = ok ? as_[c] : 0.f;
        float adv = ok ? ad_[c] : 0.f;
#pragma unroll
        for (int r = 0; r < 4; r++) {
            float v = acc[nt][r];
            if (ok) g_hBb[outb][row0 + rg * 4 + r][c] = __float2bfloat16(v);
            ps[r] += v * asv;
            pd[r] += v * adv;
        }
    }
#pragma unroll
    for (int m = 1; m < 16; m <<= 1) {
#pragma unroll
        for (int r = 0; r < 4; r++) {
            ps[r] += __shfl_xor(ps[r], m);
            pd[r] += __shfl_xor(pd[r], m);
        }
    }
    if (col == 0) {
#pragma unroll
        for (int r = 0; r < 4; r++) {
            g_hs[outb][row0 + rg * 4 + r] = ps[r];
            g_hd[outb][row0 + rg * 4 + r] = pd[r];
        }
    }
}

// ---------------- final aggregate: pooling only (no feature store) ----------
__global__ __launch_bounds__(256) void k_agg_pool(const float* __restrict__ bias,
                                                  int pool_off, int inb) {
    int lane = threadIdx.x & 63, wave = threadIdx.x >> 6;
    int p = blockIdx.x;
    int xcd = p & 7, slot = p >> 3;
    int b = xcd * 8 + (slot >> 8);         // graph (matches fused placement)
    int d = (slot & 255) * 4 + wave;
    int node = (b << 10) + d;

    int beg = g_offs[b * (N + 1) + d], end = g_offs[b * (N + 1) + d + 1];
    int deg = end - beg;
    const int* srcs = g_ssrc + b * EP;
    const float* hsb = g_hs[inb] + b * N;
    const __hip_bfloat16* hb = &g_hBb[inb][b * N][0];
    float hdv = g_hd[inb][node];

    float a0 = 0.f, a1 = 0.f, a2 = 0.f;
    float denom = 1.f;

    if (deg <= 64) {
        int sv = 0;
        float ev = -1e30f;
        if (lane < deg) {
            sv = srcs[beg + lane];
            float e = hsb[sv] + hdv;
            ev = (e > 0.f) ? e : 0.2f * e;
        }
        float m = ev;
#pragma unroll
        for (int s = 32; s > 0; s >>= 1) m = fmaxf(m, __shfl_xor(m, s));
        float wv = (lane < deg) ? __expf(ev - m) : 0.f;
        denom = wv;
#pragma unroll
        for (int s = 32; s > 0; s >>= 1) denom += __shfl_xor(denom, s);

        float b0 = 0.f, b1 = 0.f, b2 = 0.f;
        int i = 0;
        for (; i + 2 <= deg; i += 2) {
            int s0 = __shfl(sv, i), s1 = __shfl(sv, i + 1);
            float w0 = __shfl(wv, i), w1 = __shfl(wv, i + 1);
            const __hip_bfloat16* r0 = hb + s0 * H;
            const __hip_bfloat16* r1 = hb + s1 * H;
            float x00 = __bfloat162float(r0[lane]);
            float x01 = __bfloat162float(r0[lane + 64]);
            float x10 = __bfloat162float(r1[lane]);
            float x11 = __bfloat162float(r1[lane + 64]);
            float x02 = 0.f, x12 = 0.f;
            if (lane < H - 128) {
                x02 = __bfloat162float(r0[lane + 128]);
                x12 = __bfloat162float(r1[lane + 128]);
            }
            a0 += w0 * x00; a1 += w0 * x01; a2 += w0 * x02;
            b0 += w1 * x10; b1 += w1 * x11; b2 += w1 * x12;
        }
        if (i < deg) {
            int s0 = __shfl(sv, i);
            float w0 = __shfl(wv, i);
            const __hip_bfloat16* r0 = hb + s0 * H;
            a0 += w0 * __bfloat162float(r0[lane]);
            a1 += w0 * __bfloat162float(r0[lane + 64]);
            if (lane < H - 128) a2 += w0 * __bfloat162float(r0[lane + 128]);
        }
        a0 += b0; a1 += b1; a2 += b2;
    } else {
        float m = -1e30f;
        for (int i = beg; i < end; i++) {
            float e = hsb[srcs[i]] + hdv;
            e = (e > 0.f) ? e : 0.2f * e;
            m = fmaxf(m, e);
        }
        denom = 0.f;
        for (int i = beg; i < end; i++) {
            int s = srcs[i];
            float e = hsb[s] + hdv;
            e = (e > 0.f) ? e : 0.2f * e;
            float w = __expf(e - m);
            denom += w;
            const __hip_bfloat16* hr = hb + s * H;
            a0 += w * __bfloat162float(hr[lane]);
            a1 += w * __bfloat162float(hr[lane + 64]);
            if (lane < H - 128) a2 += w * __bfloat162float(hr[lane + 128]);
        }
    }

    float inv = 1.0f / denom;
    float o0 = a0 * inv + bias[lane];
    float o1 = a1 * inv + bias[lane + 64];
    float o2 = (lane < H - 128) ? (a2 * inv + bias[lane + 128]) : 0.f;

    // block-level LDS reduce, then one atomicAdd per feature per block
    __shared__ float sp[3][64];
    if (wave == 0) { sp[0][lane] = 0.f; sp[1][lane] = 0.f; sp[2][lane] = 0.f; }
    __syncthreads();
    atomicAdd(&sp[0][lane], o0);
    atomicAdd(&sp[1][lane], o1);
    if (lane < H - 128) atomicAdd(&sp[2][lane], o2);
    __syncthreads();
    if (wave == 0) {
        float* pb = g_pooled + b * FC_IN + pool_off;
        atomicAdd(&pb[lane], sp[0][lane]);
        atomicAdd(&pb[lane + 64], sp[1][lane]);
        if (lane < H - 128) atomicAdd(&pb[lane + 128], sp[2][lane]);
    }
}

// ---------------- MLP head ----------------
__global__ __launch_bounds__(256) void k_mlp(const float* __restrict__ fc1W, const float* __restrict__ fc1b,
                                             const float* __restrict__ fc2W, const float* __restrict__ fc2b,
                                             const float* __restrict__ fc3W, const float* __restrict__ fc3b,
                                             float* __restrict__ out) {
    int b = blockIdx.x, t = threadIdx.x;
    __shared__ float p[FC_IN];
    __shared__ float h1[256];
    __shared__ float h2[128];
    const float invN = 1.0f / N;
    for (int i = t; i < FC_IN; i += 256) p[i] = g_pooled[b * FC_IN + i] * invN;
    __syncthreads();
    float acc = fc1b[t];
    for (int k = 0; k < FC_IN; k++) acc += p[k] * fc1W[k * 256 + t];
    h1[t] = acc;
    __syncthreads();
    if (t < 128) {
        float a = fc2b[t];
        for (int k = 0; k < 256; k++) a += h1[k] * fc2W[k * 128 + t];
        h2[t] = a;
    }
    __syncthreads();
    if (t < NC) {
        float a = fc3b[t];
        for (int k = 0; k < 128; k++) a += h2[k] * fc3W[k * NC + t];
        out[b * NC + t] = a;
    }
}

// ---------------- launch ----------------
extern "C" void kernel_launch(void* const* d_in, const int* in_sizes, int n_in,
                              void* d_out, int out_size, void* d_ws, size_t ws_size,
                              hipStream_t stream) {
    const float* x    = (const float*)d_in[0];
    const int*   ei   = (const int*)d_in[1];
    const float* W1   = (const float*)d_in[2];
    const float* as1  = (const float*)d_in[3];
    const float* ad1  = (const float*)d_in[4];
    const float* b1   = (const float*)d_in[5];
    const float* W234 = (const float*)d_in[6];
    const float* as234= (const float*)d_in[7];
    const float* ad234= (const float*)d_in[8];
    const float* b234 = (const float*)d_in[9];
    const float* fc1W = (const float*)d_in[10];
    const float* fc1b = (const float*)d_in[11];
    const float* fc2W = (const float*)d_in[12];
    const float* fc2b = (const float*)d_in[13];
    const float* fc3W = (const float*)d_in[14];
    const float* fc3b = (const float*)d_in[15];
    float* out = (float*)d_out;

    hipLaunchKernelGGL(k_init, dim3((3 * NFRAG * 8 + 255) / 256), dim3(256), 0, stream, W234);
    hipLaunchKernelGGL(k_count, dim3((B * E + 255) / 256), dim3(256), 0, stream, ei);
    hipLaunchKernelGGL(k_scan, dim3(B), dim3(1024), 0, stream);
    hipLaunchKernelGGL(k_scatter, dim3((B * E + 255) / 256), dim3(256), 0, stream, ei);
    hipLaunchKernelGGL(k_pool_x, dim3(B), dim3(256), 0, stream, x);

    // Layer 1 transform (buffers[0])
    hipLaunchKernelGGL(k_layer1, dim3(B * N / 4), dim3(256), 0, stream, x, W1, as1, ad1);

    // Fused (agg_k + GEMM_{k+1}): k=1,2,3
    hipLaunchKernelGGL(k_fused, dim3(1024), dim3(256), 0, stream,
                       0, b1, 3, 0, as234, ad234);
    hipLaunchKernelGGL(k_fused, dim3(1024), dim3(256), 0, stream,
                       1, b234, 3 + H, 1, as234 + H, ad234 + H);
    hipLaunchKernelGGL(k_fused, dim3(1024), dim3(256), 0, stream,
                       2, b234 + H, 3 + 2 * H, 0, as234 + 2 * H, ad234 + 2 * H);

    // Final aggregate: pooling only
    hipLaunchKernelGGL(k_agg_pool, dim3(B * N / 4), dim3(256), 0, stream,
                       b234 + 2 * H, 3 + 3 * H, 1);

    hipLaunchKernelGGL(k_mlp, dim3(B), dim3(256), 0, stream,
                       fc1W, fc1b, fc2W, fc2b, fc3W, fc3b, out);
}

// Round 15
// 438.277 us; speedup vs baseline: 1.7377x; 1.3088x over previous
//
#include <hip/hip_runtime.h>
#include <hip/hip_bf16.h>

#define B 64
#define N 1024
#define E 8192
#define EP (E + N)      // 9216 edges incl self-loops
#define C 3
#define H 152
#define NC 10
#define FC_IN 611       // C + 4*H
#define NT 10           // n-tiles of 16
#define KS 5            // k-steps of 32
#define NFRAG (NT * KS * 64)   // 3200 fragments of 8 bf16
#define AP 168          // padded A-tile row length (elements)

typedef __attribute__((ext_vector_type(8))) short bf16x8;
typedef __attribute__((ext_vector_type(4))) float f32x4;

// ---------------- static scratch ----------------
__device__ __hip_bfloat16 g_hBb[2][B * N][H];      // transformed features (bf16), dbuf
__device__ float g_hs[2][B * N];
__device__ float g_hd[2][B * N];
__device__ float g_pooled[B * FC_IN];
__device__ float g_wgt[B * EP];                    // normalized edge weights (final layer)
__device__ float g_tw[B * N];                      // per-src total weight (final layer)
__device__ __hip_bfloat16 g_Wfhi[3][NFRAG * 8];    // W^T hi, fragment-ordered
__device__ __hip_bfloat16 g_Wflo[3][NFRAG * 8];    // W^T lo residual
__device__ int   g_cnt[B * N];
__device__ int   g_woff[B * N];
__device__ int   g_offs[B * (N + 1)];
__device__ int   g_ssrc[B * EP];

// ---------------- init: zero counters + pack W (merged) ----------------
__global__ void k_init(const float* __restrict__ W234) {
    int gid = blockIdx.x * 256 + threadIdx.x;
    if (gid < B * N) { g_cnt[gid] = 0; g_tw[gid] = 0.f; }
    if (gid < B * FC_IN) g_pooled[gid] = 0.f;
    if (gid < 3 * NFRAG * 8) {
        int l = gid / (NFRAG * 8);
        int rem = gid - l * (NFRAG * 8);
        int i = rem >> 3, j = rem & 7;
        int frag = i >> 6, ln = i & 63;
        int nt = frag / KS, ks = frag - nt * KS;
        int n = nt * 16 + (ln & 15);
        int kk = ks * 32 + (ln >> 4) * 8 + j;
        float v = (n < H && kk < H) ? W234[(l * H + kk) * H + n] : 0.f;
        __hip_bfloat16 hi = __float2bfloat16(v);
        float lo = v - __bfloat162float(hi);
        g_Wfhi[l][rem] = hi;
        g_Wflo[l][rem] = __float2bfloat16(lo);
    }
}

// ---------------- CSR build ----------------
__global__ void k_count(const int* __restrict__ ei) {
    int gid = blockIdx.x * 256 + threadIdx.x;
    if (gid >= B * E) return;
    int b = gid >> 13;
    int e = gid & (E - 1);
    int dst = ei[b * 2 * E + E + e];
    atomicAdd(&g_cnt[b * N + dst], 1);
}

__global__ __launch_bounds__(1024) void k_scan() {
    int b = blockIdx.x, t = threadIdx.x;
    __shared__ int s[N];
    int v = g_cnt[b * N + t] + 1;          // +1 self loop
    s[t] = v;
    __syncthreads();
    for (int d = 1; d < N; d <<= 1) {
        int add = (t >= d) ? s[t - d] : 0;
        __syncthreads();
        s[t] += add;
        __syncthreads();
    }
    int incl = s[t], excl = incl - v;
    g_offs[b * (N + 1) + t + 1] = incl;
    if (t == 0) g_offs[b * (N + 1)] = 0;
    g_ssrc[b * EP + excl] = t;             // self loop first in bucket
    g_woff[b * N + t] = excl + 1;
}

__global__ void k_scatter(const int* __restrict__ ei) {
    int gid = blockIdx.x * 256 + threadIdx.x;
    if (gid >= B * E) return;
    int b = gid >> 13;
    int e = gid & (E - 1);
    int src = ei[b * 2 * E + e];
    int dst = ei[b * 2 * E + E + e];
    int pos = atomicAdd(&g_woff[b * N + dst], 1);
    g_ssrc[b * EP + pos] = src;
}

// ---------------- x pooling ----------------
__global__ void k_pool_x(const float* __restrict__ x) {
    int b = blockIdx.x, t = threadIdx.x;
    float a0 = 0, a1 = 0, a2 = 0;
    for (int n = t; n < N; n += 256) {
        const float* p = x + (b * N + n) * C;
        a0 += p[0]; a1 += p[1]; a2 += p[2];
    }
    __shared__ float s[3][256];
    s[0][t] = a0; s[1][t] = a1; s[2][t] = a2;
    __syncthreads();
    for (int d = 128; d > 0; d >>= 1) {
        if (t < d) {
            s[0][t] += s[0][t + d];
            s[1][t] += s[1][t + d];
            s[2][t] += s[2][t + d];
        }
        __syncthreads();
    }
    if (t < 3) g_pooled[b * FC_IN + t] = s[t][0];
}

// ---------------- fused layer 1: h = x @ W1 (K=3) + hs/hd → buffers[0] -----
__global__ __launch_bounds__(256) void k_layer1(const float* __restrict__ x,
                                                const float* __restrict__ W1,
                                                const float* __restrict__ as_,
                                                const float* __restrict__ ad_) {
    int lane = threadIdx.x & 63, wave = threadIdx.x >> 6;
    int row = blockIdx.x * 4 + wave;       // < B*N
    const float* xr = x + row * C;
    float x0 = xr[0], x1 = xr[1], x2 = xr[2];
    __hip_bfloat16* hr = &g_hBb[0][row][0];
    float vs = 0.f, vd = 0.f;
#pragma unroll
    for (int seg = 0; seg < 3; seg++) {
        int j = lane + seg * 64;
        if (j < H) {
            float h = x0 * W1[j] + x1 * W1[H + j] + x2 * W1[2 * H + j];
            hr[j] = __float2bfloat16(h);
            vs += h * as_[j];
            vd += h * ad_[j];
        }
    }
#pragma unroll
    for (int d = 32; d > 0; d >>= 1) {
        vs += __shfl_xor(vs, d);
        vd += __shfl_xor(vd, d);
    }
    if (lane == 0) { g_hs[0][row] = vs; g_hd[0][row] = vd; }
}

// ---------------- FUSED v2: aggregate(layer k) + GEMM(layer k+1) ------------
// Block = 4 waves = ONE 16-node tile (shared LDS A-tile, 10.75KB):
// phase 1: wave w aggregates nodes d0+w*4+{0..3} into shared tile;
// phase 2: all waves read same A-frags (LDS broadcast), each computes its
// subset of the 10 N-tiles (W frags from L2); hs/hd combined via LDS atomics.
__global__ __launch_bounds__(256) void k_fused(int l, const float* __restrict__ bias,
                                               int pool_off, int inb,
                                               const float* __restrict__ as_,
                                               const float* __restrict__ ad_) {
    __shared__ __hip_bfloat16 sAhi[16][AP];   // 5376 B
    __shared__ __hip_bfloat16 sAlo[16][AP];   // 5376 B
    __shared__ float spd[2][16];
    int lane = threadIdx.x & 63, wave = threadIdx.x >> 6;
    int tid = threadIdx.x;
    if (tid < 32) spd[tid >> 4][tid & 15] = 0.f;

    // graph→XCD chunked: graph g served by XCD g/8
    int bid = blockIdx.x;                  // 0..4095
    int xcd = bid & 7, j = bid >> 3;       // j: 0..511
    int b = xcd * 8 + (j & 7);             // graph
    int part = j >> 3;                     // 0..63
    int d0 = part * 16;
    int tile = b * 64 + part;

    const int* offs = g_offs + b * (N + 1);
    int offl = (lane < 17) ? offs[d0 + lane] : 0;
    const int* srcs = g_ssrc + b * EP;
    const float* hsb = g_hs[inb] + b * N;
    const float* hdb = g_hd[inb] + b * N;
    const __hip_bfloat16* hb = &g_hBb[inb][b * N][0];
    float pool0 = 0.f, pool1 = 0.f, pool2 = 0.f;

    // ---------- phase 1: this wave's 4 node aggregates into shared tile ----
    for (int i4 = 0; i4 < 4; i4++) {
        int nn = wave * 4 + i4;
        int beg = __shfl(offl, nn);
        int end = __shfl(offl, nn + 1);
        int deg = end - beg;
        float hdv = hdb[d0 + nn];
        float a0 = 0.f, a1 = 0.f, a2 = 0.f;
        float denom = 1.f;

        if (deg <= 64) {
            int sv = 0;
            float ev = -1e30f;
            if (lane < deg) {
                sv = srcs[beg + lane];
                float e = hsb[sv] + hdv;
                ev = (e > 0.f) ? e : 0.2f * e;
            }
            float m = ev;
#pragma unroll
            for (int s = 32; s > 0; s >>= 1) m = fmaxf(m, __shfl_xor(m, s));
            float wv = (lane < deg) ? __expf(ev - m) : 0.f;
            denom = wv;
#pragma unroll
            for (int s = 32; s > 0; s >>= 1) denom += __shfl_xor(denom, s);

            float b0 = 0.f, b1 = 0.f, b2 = 0.f;
            float c0 = 0.f, c1 = 0.f, c2 = 0.f;
            float e0 = 0.f, e1 = 0.f, e2 = 0.f;
            int i = 0;
            for (; i + 4 <= deg; i += 4) {
                int s0 = __shfl(sv, i),     s1 = __shfl(sv, i + 1);
                int s2 = __shfl(sv, i + 2), s3 = __shfl(sv, i + 3);
                float w0 = __shfl(wv, i),     w1 = __shfl(wv, i + 1);
                float w2 = __shfl(wv, i + 2), w3 = __shfl(wv, i + 3);
                const __hip_bfloat16* r0 = hb + s0 * H;
                const __hip_bfloat16* r1 = hb + s1 * H;
                const __hip_bfloat16* r2 = hb + s2 * H;
                const __hip_bfloat16* r3 = hb + s3 * H;
                float x00 = __bfloat162float(r0[lane]);
                float x01 = __bfloat162float(r0[lane + 64]);
                float x10 = __bfloat162float(r1[lane]);
                float x11 = __bfloat162float(r1[lane + 64]);
                float x20 = __bfloat162float(r2[lane]);
                float x21 = __bfloat162float(r2[lane + 64]);
                float x30 = __bfloat162float(r3[lane]);
                float x31 = __bfloat162float(r3[lane + 64]);
                float x02 = 0.f, x12 = 0.f, x22 = 0.f, x32 = 0.f;
                if (lane < H - 128) {
                    x02 = __bfloat162float(r0[lane + 128]);
                    x12 = __bfloat162float(r1[lane + 128]);
                    x22 = __bfloat162float(r2[lane + 128]);
                    x32 = __bfloat162float(r3[lane + 128]);
                }
                a0 += w0 * x00; a1 += w0 * x01; a2 += w0 * x02;
                b0 += w1 * x10; b1 += w1 * x11; b2 += w1 * x12;
                c0 += w2 * x20; c1 += w2 * x21; c2 += w2 * x22;
                e0 += w3 * x30; e1 += w3 * x31; e2 += w3 * x32;
            }
            for (; i + 2 <= deg; i += 2) {
                int s0 = __shfl(sv, i), s1 = __shfl(sv, i + 1);
                float w0 = __shfl(wv, i), w1 = __shfl(wv, i + 1);
                const __hip_bfloat16* r0 = hb + s0 * H;
                const __hip_bfloat16* r1 = hb + s1 * H;
                float x00 = __bfloat162float(r0[lane]);
                float x01 = __bfloat162float(r0[lane + 64]);
                float x10 = __bfloat162float(r1[lane]);
                float x11 = __bfloat162float(r1[lane + 64]);
                float x02 = 0.f, x12 = 0.f;
                if (lane < H - 128) {
                    x02 = __bfloat162float(r0[lane + 128]);
                    x12 = __bfloat162float(r1[lane + 128]);
                }
                a0 += w0 * x00; a1 += w0 * x01; a2 += w0 * x02;
                b0 += w1 * x10; b1 += w1 * x11; b2 += w1 * x12;
            }
            if (i < deg) {
                int s0 = __shfl(sv, i);
                float w0 = __shfl(wv, i);
                const __hip_bfloat16* r0 = hb + s0 * H;
                a0 += w0 * __bfloat162float(r0[lane]);
                a1 += w0 * __bfloat162float(r0[lane + 64]);
                if (lane < H - 128) a2 += w0 * __bfloat162float(r0[lane + 128]);
            }
            a0 += b0 + c0 + e0; a1 += b1 + c1 + e1; a2 += b2 + c2 + e2;
        } else {
            float m = -1e30f;
            for (int i = beg; i < end; i++) {
                float e = hsb[srcs[i]] + hdv;
                e = (e > 0.f) ? e : 0.2f * e;
                m = fmaxf(m, e);
            }
            denom = 0.f;
            for (int i = beg; i < end; i++) {
                int s = srcs[i];
                float e = hsb[s] + hdv;
                e = (e > 0.f) ? e : 0.2f * e;
                float w = __expf(e - m);
                denom += w;
                const __hip_bfloat16* hr = hb + s * H;
                a0 += w * __bfloat162float(hr[lane]);
                a1 += w * __bfloat162float(hr[lane + 64]);
                if (lane < H - 128) a2 += w * __bfloat162float(hr[lane + 128]);
            }
        }

        float inv = 1.0f / denom;
        float o0 = a0 * inv + bias[lane];
        float o1 = a1 * inv + bias[lane + 64];
        float o2 = (lane < H - 128) ? (a2 * inv + bias[lane + 128]) : 0.f;
        pool0 += o0; pool1 += o1; pool2 += o2;

        __hip_bfloat16 h0 = __float2bfloat16(o0);
        __hip_bfloat16 h1 = __float2bfloat16(o1);
        __hip_bfloat16 h2 = __float2bfloat16(o2);      // 0 on pad lanes
        sAhi[nn][lane] = h0;
        sAlo[nn][lane] = __float2bfloat16(o0 - __bfloat162float(h0));
        sAhi[nn][lane + 64] = h1;
        sAlo[nn][lane + 64] = __float2bfloat16(o1 - __bfloat162float(h1));
        if (lane < AP - 128) {   // lanes 0..39 cover f = 128..167 (zero-padded)
            sAhi[nn][lane + 128] = h2;
            sAlo[nn][lane + 128] = __float2bfloat16(o2 - __bfloat162float(h2));
        }
    }

    // per-wave pooled atomics (4 nodes each)
    {
        float* pb = g_pooled + b * FC_IN + pool_off;
        atomicAdd(&pb[lane], pool0);
        atomicAdd(&pb[lane + 64], pool1);
        if (lane < H - 128) atomicAdd(&pb[lane + 128], pool2);
    }
    __syncthreads();

    // ---------- phase 2: nt-split MFMA GEMM (A from shared LDS, W from L2) --
    int outb = inb ^ 1;
    bf16x8 ahi[KS], alo[KS];
#pragma unroll
    for (int ks = 0; ks < KS; ks++) {
        int off = (lane & 15) * AP + ks * 32 + (lane >> 4) * 8;
        ahi[ks] = *(const bf16x8*)&sAhi[0][off];
        alo[ks] = *(const bf16x8*)&sAlo[0][off];
    }
    const __hip_bfloat16* Wh = g_Wfhi[l];
    const __hip_bfloat16* Wl = g_Wflo[l];
    int ntbeg = (wave < 2) ? wave * 3 : 6 + (wave - 2) * 2;
    int ntcnt = (wave < 2) ? 3 : 2;

    f32x4 acc[3];
#pragma unroll
    for (int k = 0; k < 3; k++) acc[k] = (f32x4){0.f, 0.f, 0.f, 0.f};
#pragma unroll
    for (int ks = 0; ks < KS; ks++) {
#pragma unroll
        for (int k = 0; k < 3; k++) {
            if (k < ntcnt) {
                int nt = ntbeg + k;
                bf16x8 bh = *(const bf16x8*)&Wh[((nt * KS + ks) * 64 + lane) * 8];
                bf16x8 bl = *(const bf16x8*)&Wl[((nt * KS + ks) * 64 + lane) * 8];
                acc[k] = __builtin_amdgcn_mfma_f32_16x16x32_bf16(ahi[ks], bh, acc[k], 0, 0, 0);
                acc[k] = __builtin_amdgcn_mfma_f32_16x16x32_bf16(alo[ks], bh, acc[k], 0, 0, 0);
                acc[k] = __builtin_amdgcn_mfma_f32_16x16x32_bf16(ahi[ks], bl, acc[k], 0, 0, 0);
            }
        }
    }

    // epilogue: bf16 D store + hs/hd partials (C/D: col=lane&15, row=(lane>>4)*4+reg)
    int row0 = tile * 16;
    int col = lane & 15, rg = lane >> 4;
    float ps[4] = {0, 0, 0, 0}, pd[4] = {0, 0, 0, 0};
#pragma unroll
    for (int k = 0; k < 3; k++) {
        if (k < ntcnt) {
            int nt = ntbeg + k;
            int c = nt * 16 + col;
            bool ok = c < H;
            float asv = ok ? as_[c] : 0.f;
            float adv = ok ? ad_[c] : 0.f;
#pragma unroll
            for (int r = 0; r < 4; r++) {
                float v = acc[k][r];
                if (ok) g_hBb[outb][row0 + rg * 4 + r][c] = __float2bfloat16(v);
                ps[r] += v * asv;
                pd[r] += v * adv;
            }
        }
    }
#pragma unroll
    for (int m = 1; m < 16; m <<= 1) {
#pragma unroll
        for (int r = 0; r < 4; r++) {
            ps[r] += __shfl_xor(ps[r], m);
            pd[r] += __shfl_xor(pd[r], m);
        }
    }
    if (col == 0) {
#pragma unroll
        for (int r = 0; r < 4; r++) {
            atomicAdd(&spd[0][rg * 4 + r], ps[r]);
            atomicAdd(&spd[1][rg * 4 + r], pd[r]);
        }
    }
    __syncthreads();
    if (tid < 16) {
        g_hs[outb][row0 + tid] = spd[0][tid];
        g_hd[outb][row0 + tid] = spd[1][tid];
    }
}

// ---------------- final layer: edge weights (normalized) --------------------
__global__ __launch_bounds__(256) void k_edgew(int inb) {
    int lane = threadIdx.x & 63, wave = threadIdx.x >> 6;
    int p = blockIdx.x;
    int xcd = p & 7, slot = p >> 3;
    int b = xcd * 8 + (slot >> 8);
    int d = (slot & 255) * 4 + wave;
    int node = (b << 10) + d;

    int beg = g_offs[b * (N + 1) + d], end = g_offs[b * (N + 1) + d + 1];
    int deg = end - beg;
    const int* srcs = g_ssrc + b * EP;
    const float* hsb = g_hs[inb] + b * N;
    float* wgt = g_wgt + b * EP;
    float hdv = g_hd[inb][node];

    if (deg <= 64) {
        float ev = -1e30f;
        if (lane < deg) {
            int sv = srcs[beg + lane];
            float e = hsb[sv] + hdv;
            ev = (e > 0.f) ? e : 0.2f * e;
        }
        float m = ev;
#pragma unroll
        for (int s = 32; s > 0; s >>= 1) m = fmaxf(m, __shfl_xor(m, s));
        float wv = (lane < deg) ? __expf(ev - m) : 0.f;
        float denom = wv;
#pragma unroll
        for (int s = 32; s > 0; s >>= 1) denom += __shfl_xor(denom, s);
        if (lane < deg) wgt[beg + lane] = wv / denom;
    } else {
        float m = -1e30f;
        for (int i = beg + lane; i < end; i += 64) {
            float e = hsb[srcs[i]] + hdv;
            e = (e > 0.f) ? e : 0.2f * e;
            m = fmaxf(m, e);
        }
#pragma unroll
        for (int s = 32; s > 0; s >>= 1) m = fmaxf(m, __shfl_xor(m, s));
        float denom = 0.f;
        for (int i = beg + lane; i < end; i += 64) {
            float e = hsb[srcs[i]] + hdv;
            e = (e > 0.f) ? e : 0.2f * e;
            denom += __expf(e - m);
        }
#pragma unroll
        for (int s = 32; s > 0; s >>= 1) denom += __shfl_xor(denom, s);
        float inv = 1.0f / denom;
        for (int i = beg + lane; i < end; i += 64) {
            float e = hsb[srcs[i]] + hdv;
            e = (e > 0.f) ? e : 0.2f * e;
            wgt[i] = __expf(e - m) * inv;
        }
    }
}

// ---------------- final layer: per-src weight totals ------------------------
__global__ void k_wsum() {
    int gid = blockIdx.x * 256 + threadIdx.x;
    if (gid >= B * EP) return;
    int b = gid / EP;
    atomicAdd(&g_tw[b * N + g_ssrc[gid]], g_wgt[gid]);
}

// ---------------- final layer: pooled output = sum_s t[s]*h[s] + N*bias -----
__global__ __launch_bounds__(192) void k_poolw(const float* __restrict__ bias,
                                               int pool_off, int inb) {
    int b = blockIdx.x >> 2, chunk = blockIdx.x & 3;
    int j = threadIdx.x;
    if (j >= H) return;
    const float* tw = g_tw + b * N + chunk * 256;
    const __hip_bfloat16* hb = &g_hBb[inb][b * N + chunk * 256][0];
    float acc = 0.f;
    for (int n = 0; n < 256; n++)
        acc += tw[n] * __bfloat162float(hb[n * H + j]);
    if (chunk == 0) acc += (float)N * bias[j];
    atomicAdd(&g_pooled[b * FC_IN + pool_off + j], acc);
}

// ---------------- MLP head ----------------
__global__ __launch_bounds__(256) void k_mlp(const float* __restrict__ fc1W, const float* __restrict__ fc1b,
                                             const float* __restrict__ fc2W, const float* __restrict__ fc2b,
                                             const float* __restrict__ fc3W, const float* __restrict__ fc3b,
                                             float* __restrict__ out) {
    int b = blockIdx.x, t = threadIdx.x;
    __shared__ float p[FC_IN];
    __shared__ float h1[256];
    __shared__ float h2[128];
    const float invN = 1.0f / N;
    for (int i = t; i < FC_IN; i += 256) p[i] = g_pooled[b * FC_IN + i] * invN;
    __syncthreads();
    float acc = fc1b[t];
    for (int k = 0; k < FC_IN; k++) acc += p[k] * fc1W[k * 256 + t];
    h1[t] = acc;
    __syncthreads();
    if (t < 128) {
        float a = fc2b[t];
        for (int k = 0; k < 256; k++) a += h1[k] * fc2W[k * 128 + t];
        h2[t] = a;
    }
    __syncthreads();
    if (t < NC) {
        float a = fc3b[t];
        for (int k = 0; k < 128; k++) a += h2[k] * fc3W[k * NC + t];
        out[b * NC + t] = a;
    }
}

// ---------------- launch ----------------
extern "C" void kernel_launch(void* const* d_in, const int* in_sizes, int n_in,
                              void* d_out, int out_size, void* d_ws, size_t ws_size,
                              hipStream_t stream) {
    const float* x    = (const float*)d_in[0];
    const int*   ei   = (const int*)d_in[1];
    const float* W1   = (const float*)d_in[2];
    const float* as1  = (const float*)d_in[3];
    const float* ad1  = (const float*)d_in[4];
    const float* b1   = (const float*)d_in[5];
    const float* W234 = (const float*)d_in[6];
    const float* as234= (const float*)d_in[7];
    const float* ad234= (const float*)d_in[8];
    const float* b234 = (const float*)d_in[9];
    const float* fc1W = (const float*)d_in[10];
    const float* fc1b = (const float*)d_in[11];
    const float* fc2W = (const float*)d_in[12];
    const float* fc2b = (const float*)d_in[13];
    const float* fc3W = (const float*)d_in[14];
    const float* fc3b = (const float*)d_in[15];
    float* out = (float*)d_out;

    hipLaunchKernelGGL(k_init, dim3((3 * NFRAG * 8 + 255) / 256), dim3(256), 0, stream, W234);
    hipLaunchKernelGGL(k_count, dim3((B * E + 255) / 256), dim3(256), 0, stream, ei);
    hipLaunchKernelGGL(k_scan, dim3(B), dim3(1024), 0, stream);
    hipLaunchKernelGGL(k_scatter, dim3((B * E + 255) / 256), dim3(256), 0, stream, ei);
    hipLaunchKernelGGL(k_pool_x, dim3(B), dim3(256), 0, stream, x);

    // Layer 1 transform (buffers[0])
    hipLaunchKernelGGL(k_layer1, dim3(B * N / 4), dim3(256), 0, stream, x, W1, as1, ad1);

    // Fused (agg_k + GEMM_{k+1}): k=1,2,3
    hipLaunchKernelGGL(k_fused, dim3(4096), dim3(256), 0, stream,
                       0, b1, 3, 0, as234, ad234);
    hipLaunchKernelGGL(k_fused, dim3(4096), dim3(256), 0, stream,
                       1, b234, 3 + H, 1, as234 + H, ad234 + H);
    hipLaunchKernelGGL(k_fused, dim3(4096), dim3(256), 0, stream,
                       2, b234 + H, 3 + 2 * H, 0, as234 + 2 * H, ad234 + 2 * H);

    // Final layer: pooled output only, via per-src weight totals
    hipLaunchKernelGGL(k_edgew, dim3(B * N / 4), dim3(256), 0, stream, 1);
    hipLaunchKernelGGL(k_wsum, dim3((B * EP + 255) / 256), dim3(256), 0, stream);
    hipLaunchKernelGGL(k_poolw, dim3(B * 4), dim3(192), 0, stream,
                       b234 + 2 * H, 3 + 3 * H, 1);

    hipLaunchKernelGGL(k_mlp, dim3(B), dim3(256), 0, stream,
                       fc1W, fc1b, fc2W, fc2b, fc3W, fc3b, out);
}